// Round 2
// baseline (958.890 us; speedup 1.0000x reference)
//
#include <hip/hip_runtime.h>

// Problem: MyStrategicModel_35691178229867
// B=524288 independent 2-D samples; 11 CCP rounds x 100 PGA steps + 200 final steps.
// Pure fp32 VALU-bound. Exact-order mirror of the numpy reference.
// File-scope pragma: no FMA contraction anywhere in this TU (matches numpy's
// separate mul/add rounding). R1 fix: pragma was illegally mid-block; now file scope.
#pragma clang fp contract(off)

#define XLO -10.0f
#define XHI 10.0f

struct Params {
    float w0, w1, b, v0, v1, r0, r1;
};

// fd = f'(x) = (0.5 * (s / sqrt(s*s+1))) * w,  s = score + 1   (slope == 1)
__device__ __forceinline__ void fder(float x0, float x1, const Params& p,
                                     float& fd0, float& fd1) {
    float score = (x0 * p.w0 + x1 * p.w1) + p.b;
    float s = score + 1.0f;
    float coef = 0.5f * (s / sqrtf(s * s + 1.0f));
    fd0 = coef * p.w0;
    fd1 = coef * p.w1;
}

// Projected gradient ascent, n steps, starting from clip(r). Mirrors numpy op order.
__device__ __forceinline__ void solve_inner(float& ox0, float& ox1,
                                            float fd0, float fd1,
                                            const Params& p, int n) {
    float x0 = fminf(fmaxf(p.r0, XLO), XHI);
    float x1 = fminf(fmaxf(p.r1, XLO), XHI);
    for (int k = 0; k < n; ++k) {
        // g'(x): s = score - 1
        float score = (x0 * p.w0 + x1 * p.w1) + p.b;
        float s = score - 1.0f;
        float gcoef = 0.5f * (s / sqrtf(s * s + 1.0f));
        float g0 = gcoef * p.w0;
        float g1 = gcoef * p.w1;
        // c'(x): COST*(2*EPS*d + (1-EPS)*pos*v) = 0.5*((0.1*d) + (0.95*pos)*v)
        float d0 = x0 - p.r0;
        float d1 = x1 - p.r1;
        float dv = d0 * p.v0 + d1 * p.v1;
        float pos = (dv > 0.0f) ? 1.0f : 0.0f;
        float pv = 0.95f * pos;
        float c0 = 0.5f * ((0.1f * d0) + pv * p.v0);
        float c1 = 0.5f * ((0.1f * d1) + pv * p.v1);
        // grad = fd - g_grad - c_grad ; x = clip(x + grad)
        float gr0 = (fd0 - g0) - c0;
        float gr1 = (fd1 - g1) - c1;
        x0 = fminf(fmaxf(x0 + gr0, XLO), XHI);
        x1 = fminf(fmaxf(x1 + gr1, XLO), XHI);
    }
    ox0 = x0;
    ox1 = x1;
}

__global__ __launch_bounds__(256, 8)
void strategic_kernel(const float* __restrict__ X,
                      const float* __restrict__ wp,
                      const float* __restrict__ bp,
                      const float* __restrict__ vp,
                      float* __restrict__ out, int B) {
    int i = blockIdx.x * blockDim.x + threadIdx.x;
    if (i >= B) return;

    Params p;
    p.w0 = wp[0];
    p.w1 = wp[1];
    p.b  = bp[0];
    p.v0 = vp[0];
    p.v1 = vp[1];

    float2 r = reinterpret_cast<const float2*>(X)[i];
    p.r0 = r.x;
    p.r1 = r.y;

    // CCP fixed-point loop: xt starts at X; each round linearizes f at xt and
    // runs a 100-step inner solve from clip(X).
    float xt0 = p.r0, xt1 = p.r1;
    float fd0, fd1;
    for (int c = 0; c < 11; ++c) {
        fder(xt0, xt1, p, fd0, fd1);
        solve_inner(xt0, xt1, fd0, fd1, p, 100);
    }

    // Final (differentiable) solve: 200 steps with fd at the CCP fixed point.
    fder(xt0, xt1, p, fd0, fd1);
    float xo0, xo1;
    solve_inner(xo0, xo1, fd0, fd1, p, 200);

    out[i] = (xo0 * p.w0 + xo1 * p.w1) + p.b;
}

extern "C" void kernel_launch(void* const* d_in, const int* in_sizes, int n_in,
                              void* d_out, int out_size, void* d_ws, size_t ws_size,
                              hipStream_t stream) {
    const float* X = (const float*)d_in[0];
    const float* w = (const float*)d_in[1];
    const float* b = (const float*)d_in[2];
    const float* v = (const float*)d_in[3];
    float* out = (float*)d_out;

    int B = in_sizes[0] / 2;  // X is [B, 2]
    int block = 256;
    int grid = (B + block - 1) / block;
    strategic_kernel<<<grid, block, 0, stream>>>(X, w, b, v, out, B);
}

// Round 3
// 456.358 us; speedup vs baseline: 2.1012x; 2.1012x over previous
//
#include <hip/hip_runtime.h>

// Problem: MyStrategicModel_35691178229867
// B=524288 independent 2-D samples; 11 CCP rounds x 100 PGA steps + 200 final steps.
// Pure fp32 VALU-issue-bound (R2: VALUBusy ~113%, HBM 0.05%).
// R3: algebraic restructure. Per-step update collapses to
//   x' = clamp(0.95*x + e - gc*hw - pos*k),  e = fd + 0.05*r (hoisted),
//   gc = s/sqrt(s^2+1) via v_rsq_f32 + 1 Newton iter, hw = 0.5*w, k = 0.475*v.
// FMA contraction allowed (default). ~24 VALU/step vs ~45 in R2.

#define XLO -10.0f
#define XHI 10.0f

struct Params {
    float w0, w1, v0, v1, r0, r1;
    float bm1, bp1;   // b - 1 (g'), b + 1 (f')
    float hw0, hw1;   // 0.5 * w
    float k0, k1;     // 0.475 * v  (= COST*(1-EPS)*v)
};

// rsqrt with one Newton-Raphson refinement (~0.5 ulp)
__device__ __forceinline__ float rsq_nr(float t) {
    float y = __builtin_amdgcn_rsqf(t);
    float u = t * y;
    float c = __builtin_fmaf(-0.5f * u, y, 1.5f);
    return y * c;
}

// fd = f'(x) = 0.5 * (s/sqrt(s*s+1)) * w,  s = score + 1. Called 12x/thread:
// keep the precise IEEE form here (cost negligible).
__device__ __forceinline__ void fder(float x0, float x1, const Params& p,
                                     float& fd0, float& fd1) {
    float s = __builtin_fmaf(x0, p.w0, __builtin_fmaf(x1, p.w1, p.bp1));
    float coef = 0.5f * (s / sqrtf(__builtin_fmaf(s, s, 1.0f)));
    fd0 = coef * p.w0;
    fd1 = coef * p.w1;
}

__device__ __forceinline__ void solve_inner(float& ox0, float& ox1,
                                            float fd0, float fd1,
                                            const Params& p, int n) {
    float x0 = fminf(fmaxf(p.r0, XLO), XHI);
    float x1 = fminf(fmaxf(p.r1, XLO), XHI);
    const float e0 = __builtin_fmaf(0.05f, p.r0, fd0);
    const float e1 = __builtin_fmaf(0.05f, p.r1, fd1);
    for (int k = 0; k < n; ++k) {
        // s = score - 1
        float s = __builtin_fmaf(x0, p.w0, __builtin_fmaf(x1, p.w1, p.bm1));
        float t = __builtin_fmaf(s, s, 1.0f);
        float gc = s * rsq_nr(t);           // s/sqrt(s^2+1); 0.5 folded into hw
        // kink indicator
        float d0 = x0 - p.r0, d1 = x1 - p.r1;
        float dv = __builtin_fmaf(d1, p.v1, d0 * p.v0);
        bool pos = dv > 0.0f;
        float kk0 = pos ? p.k0 : 0.0f;
        float kk1 = pos ? p.k1 : 0.0f;
        // x' = clamp(0.95*x + e - gc*hw - kk)   (compiler emits v_med3 for clamp)
        float t0 = __builtin_fmaf(0.95f, x0, e0);
        t0 = __builtin_fmaf(-gc, p.hw0, t0) - kk0;
        float t1 = __builtin_fmaf(0.95f, x1, e1);
        t1 = __builtin_fmaf(-gc, p.hw1, t1) - kk1;
        x0 = fminf(fmaxf(t0, XLO), XHI);
        x1 = fminf(fmaxf(t1, XLO), XHI);
    }
    ox0 = x0;
    ox1 = x1;
}

__global__ __launch_bounds__(256, 8)
void strategic_kernel(const float* __restrict__ X,
                      const float* __restrict__ wp,
                      const float* __restrict__ bp,
                      const float* __restrict__ vp,
                      float* __restrict__ out, int B) {
    int i = blockIdx.x * blockDim.x + threadIdx.x;
    if (i >= B) return;

    Params p;
    p.w0 = wp[0];
    p.w1 = wp[1];
    float b = bp[0];
    p.v0 = vp[0];
    p.v1 = vp[1];
    p.bm1 = b - 1.0f;
    p.bp1 = b + 1.0f;
    p.hw0 = 0.5f * p.w0;
    p.hw1 = 0.5f * p.w1;
    p.k0 = 0.475f * p.v0;   // COST*(1-EPS) = 0.5*0.95
    p.k1 = 0.475f * p.v1;

    float2 r = reinterpret_cast<const float2*>(X)[i];
    p.r0 = r.x;
    p.r1 = r.y;

    // CCP fixed-point loop
    float xt0 = p.r0, xt1 = p.r1;
    float fd0, fd1;
    for (int c = 0; c < 11; ++c) {
        fder(xt0, xt1, p, fd0, fd1);
        solve_inner(xt0, xt1, fd0, fd1, p, 100);
    }

    // Final (differentiable) solve: 200 steps
    fder(xt0, xt1, p, fd0, fd1);
    float xo0, xo1;
    solve_inner(xo0, xo1, fd0, fd1, p, 200);

    out[i] = __builtin_fmaf(xo0, p.w0, __builtin_fmaf(xo1, p.w1, b));
}

extern "C" void kernel_launch(void* const* d_in, const int* in_sizes, int n_in,
                              void* d_out, int out_size, void* d_ws, size_t ws_size,
                              hipStream_t stream) {
    const float* X = (const float*)d_in[0];
    const float* w = (const float*)d_in[1];
    const float* b = (const float*)d_in[2];
    const float* v = (const float*)d_in[3];
    float* out = (float*)d_out;

    int B = in_sizes[0] / 2;  // X is [B, 2]
    int block = 256;
    int grid = (B + block - 1) / block;
    strategic_kernel<<<grid, block, 0, stream>>>(X, w, b, v, out, B);
}

// Round 4
// 296.644 us; speedup vs baseline: 3.2325x; 1.5384x over previous
//
#include <hip/hip_runtime.h>

// Problem: MyStrategicModel_35691178229867
// B=524288 independent 2-D samples; 12 solve rounds (11 CCP x 100 + 1 final x 200).
// Pure fp32 VALU-issue-bound (R3: VALUBusy ~106%, HBM 0.12%, 456 us).
// R4: lean step (16 VALU vs 23): q via folded fma, kink folded into cndmask'd
// additive constant, raw v_rsq in the loop (error ~1e-6, absmax is floor-bound),
// 2 samples/thread for ILP. Exact box-clip semantics preserved.

#define XLO -10.0f
#define XHI 10.0f
#define NS 2

__device__ __forceinline__ float rsq_nr(float t) {
    float y = __builtin_amdgcn_rsqf(t);
    float c = __builtin_fmaf(-0.5f * (t * y), y, 1.5f);
    return y * c;
}

__device__ __forceinline__ float clampx(float x) {
    return fminf(fmaxf(x, XLO), XHI);
}

__global__ __launch_bounds__(256, 8)
void strategic_kernel(const float* __restrict__ X,
                      const float* __restrict__ wp,
                      const float* __restrict__ bp,
                      const float* __restrict__ vp,
                      float* __restrict__ out, int B2) {
    int i = blockIdx.x * blockDim.x + threadIdx.x;
    if (i >= B2) return;

    const float w0 = wp[0], w1 = wp[1], b = bp[0], v0 = vp[0], v1 = vp[1];
    const float bm1 = b - 1.0f;          // score-1 bias (g')
    const float bp1 = b + 1.0f;          // score+1 bias (f')
    const float hw0 = 0.5f * w0, hw1 = 0.5f * w1;
    const float k0 = 0.475f * v0, k1 = 0.475f * v1;  // COST*(1-EPS)*v

    // Per-sample persistent state (2 samples: rows i and i+B2, both coalesced)
    float sx0[NS], sx1[NS];    // clip(r): inner-solve start point (fixed)
    float mvr[NS];             // -(v·r): kink scalar bias
    float p5r0[NS], p5r1[NS];  // 0.05*r
    float xt0[NS], xt1[NS];    // CCP linearization point (starts at r, unclipped)

#pragma unroll
    for (int s = 0; s < NS; ++s) {
        float2 r = reinterpret_cast<const float2*>(X)[i + s * B2];
        sx0[s] = clampx(r.x);
        sx1[s] = clampx(r.y);
        mvr[s] = -(__builtin_fmaf(r.y, v1, r.x * v0));
        p5r0[s] = 0.05f * r.x;
        p5r1[s] = 0.05f * r.y;
        xt0[s] = r.x;
        xt1[s] = r.y;
    }

    // 12 rounds: rounds 0..10 = CCP inner solves (100 steps each),
    // round 11 = final differentiable solve (200 steps). Each round:
    // linearize f at xt -> fd; solve from clip(r); xt <- result.
    for (int c = 0; c < 12; ++c) {
        const int nsteps = (c == 11) ? 200 : 100;

        float e0[NS], e1[NS], e0k[NS], e1k[NS], x0[NS], x1[NS];
#pragma unroll
        for (int s = 0; s < NS; ++s) {
            // fd = 0.5 * (sp/sqrt(sp^2+1)) * w,  sp = score(xt)+1
            float sp = __builtin_fmaf(xt0[s], w0, __builtin_fmaf(xt1[s], w1, bp1));
            float fc = 0.5f * sp * rsq_nr(__builtin_fmaf(sp, sp, 1.0f));
            // e = fd + 0.05*r  (additive constant of the PGA step)
            e0[s] = __builtin_fmaf(fc, w0, p5r0[s]);
            e1[s] = __builtin_fmaf(fc, w1, p5r1[s]);
            e0k[s] = e0[s] - k0;   // pos-branch constant
            e1k[s] = e1[s] - k1;
            x0[s] = sx0[s];
            x1[s] = sx1[s];
        }

        for (int k = 0; k < nsteps; ++k) {
#pragma unroll
            for (int s = 0; s < NS; ++s) {
                // tau = score - 1 ; gc = tau/sqrt(tau^2+1)  (0.5 folded into hw)
                float tau = __builtin_fmaf(x0[s], w0, __builtin_fmaf(x1[s], w1, bm1));
                float gc = tau * __builtin_amdgcn_rsqf(__builtin_fmaf(tau, tau, 1.0f));
                // kink scalar q = v·(x - r)
                float q = __builtin_fmaf(x0[s], v0, __builtin_fmaf(x1[s], v1, mvr[s]));
                bool pos = q > 0.0f;
                float a0 = pos ? e0k[s] : e0[s];
                float a1 = pos ? e1k[s] : e1[s];
                // x' = clip(0.95*x + a - gc*hw)
                float t0 = __builtin_fmaf(0.95f, x0[s], a0);
                x0[s] = clampx(__builtin_fmaf(-gc, hw0, t0));
                float t1 = __builtin_fmaf(0.95f, x1[s], a1);
                x1[s] = clampx(__builtin_fmaf(-gc, hw1, t1));
            }
        }

#pragma unroll
        for (int s = 0; s < NS; ++s) {
            xt0[s] = x0[s];
            xt1[s] = x1[s];
        }
    }

#pragma unroll
    for (int s = 0; s < NS; ++s) {
        out[i + s * B2] = __builtin_fmaf(xt0[s], w0, __builtin_fmaf(xt1[s], w1, b));
    }
}

extern "C" void kernel_launch(void* const* d_in, const int* in_sizes, int n_in,
                              void* d_out, int out_size, void* d_ws, size_t ws_size,
                              hipStream_t stream) {
    const float* X = (const float*)d_in[0];
    const float* w = (const float*)d_in[1];
    const float* b = (const float*)d_in[2];
    const float* v = (const float*)d_in[3];
    float* out = (float*)d_out;

    int B = in_sizes[0] / 2;   // X is [B, 2]
    int B2 = B / 2;            // 2 samples per thread
    int block = 256;
    int grid = (B2 + block - 1) / block;
    strategic_kernel<<<grid, block, 0, stream>>>(X, w, b, v, out, B2);
}

// Round 5
// 292.508 us; speedup vs baseline: 3.2782x; 1.0141x over previous
//
#include <hip/hip_runtime.h>

// Problem: MyStrategicModel_35691178229867
// R4 post-mortem: at ~95% of the scalar VALU-issue roofline at the throttled
// sustained clock (~1.57 GHz, consistent with m07's 103 TF scalar-FMA ceiling).
// R5: pack the 2 samples/thread into float2 ext-vectors so LLVM can select
// VOP3P v_pk_fma_f32 / v_pk_mul_f32 (gfx90a+). 10 pk ops replace 20 scalar
// fma/mul per step; rsq/cmp/cndmask/med3 stay scalar. Hypothesis test: pk f32
// full-rate on gfx950 => ~-30%; dual-pass => neutral.
// Per-component pk_fma is IEEE fma => bitwise-identical to R4.

#define XLO -10.0f
#define XHI 10.0f

typedef float v2 __attribute__((ext_vector_type(2)));

__device__ __forceinline__ v2 fma2(v2 a, v2 b, v2 c) {
    return __builtin_elementwise_fma(a, b, c);
}

__device__ __forceinline__ float clampx(float x) {
    return fminf(fmaxf(x, XLO), XHI);   // v_med3_f32
}

__device__ __forceinline__ v2 clamp2(v2 x) {
    v2 r;
    r.x = clampx(x.x);
    r.y = clampx(x.y);
    return r;
}

__device__ __forceinline__ float rsq_nr(float t) {
    float y = __builtin_amdgcn_rsqf(t);
    float c = __builtin_fmaf(-0.5f * (t * y), y, 1.5f);
    return y * c;
}

__global__ __launch_bounds__(256, 8)
void strategic_kernel(const float* __restrict__ X,
                      const float* __restrict__ wp,
                      const float* __restrict__ bp,
                      const float* __restrict__ vp,
                      float* __restrict__ out, int B2) {
    int i = blockIdx.x * blockDim.x + threadIdx.x;
    if (i >= B2) return;

    const float w0 = wp[0], w1 = wp[1], b = bp[0], v0 = vp[0], v1 = vp[1];

    // Splat wave-uniform params to v2 (hoisted out of the loop by LICM).
    const v2 w0s = w0, w1s = w1, v0s = v0, v1s = v1;
    const v2 bm1s = b - 1.0f;            // score-1 bias (g')
    const v2 bp1s = b + 1.0f;            // score+1 bias (f')
    const v2 hw0s = 0.5f * w0, hw1s = 0.5f * w1;
    const v2 k0s = 0.475f * v0, k1s = 0.475f * v1;   // COST*(1-EPS)*v
    const v2 c95 = 0.95f, one = 1.0f, half = 0.5f, c05 = 0.05f;

    // Samples 2i and 2i+1: one float4 load, components (x,y) and (z,w).
    float4 r4 = reinterpret_cast<const float4*>(X)[i];
    v2 r0, r1;
    r0.x = r4.x; r0.y = r4.z;   // coord 0 of both samples
    r1.x = r4.y; r1.y = r4.w;   // coord 1 of both samples

    const v2 sx0 = clamp2(r0), sx1 = clamp2(r1);       // inner-solve start
    // mvr = -(v.r), mirroring R4 op order: -(fma(r1, v1, r0*v0))
    v2 mvr;
    mvr.x = -(__builtin_fmaf(r1.x, v1, r0.x * v0));
    mvr.y = -(__builtin_fmaf(r1.y, v1, r0.y * v0));
    const v2 p5r0 = c05 * r0, p5r1 = c05 * r1;          // 0.05*r
    v2 xt0 = r0, xt1 = r1;                              // CCP linearization pt

    // 12 rounds: 11 CCP x 100 steps + final x 200 steps.
    for (int c = 0; c < 12; ++c) {
        const int nsteps = (c == 11) ? 200 : 100;

        // fder at xt (12 calls total; NR-refined rsq, cost negligible)
        v2 sp = fma2(xt0, w0s, fma2(xt1, w1s, bp1s));
        v2 tt = fma2(sp, sp, one);
        v2 rs;
        rs.x = rsq_nr(tt.x);
        rs.y = rsq_nr(tt.y);
        v2 fc = half * sp * rs;
        v2 e0 = fma2(fc, w0s, p5r0);
        v2 e1 = fma2(fc, w1s, p5r1);
        v2 e0k = e0 - k0s;
        v2 e1k = e1 - k1s;

        v2 x0 = sx0, x1 = sx1;
        for (int k = 0; k < nsteps; ++k) {
            // tau = score - 1 ; gc = tau/sqrt(tau^2+1)
            v2 tau = fma2(x0, w0s, fma2(x1, w1s, bm1s));
            v2 t2 = fma2(tau, tau, one);
            v2 rq;
            rq.x = __builtin_amdgcn_rsqf(t2.x);
            rq.y = __builtin_amdgcn_rsqf(t2.y);
            v2 gc = tau * rq;
            // kink scalar q = v.(x - r)
            v2 q = fma2(x0, v0s, fma2(x1, v1s, mvr));
            v2 a0, a1;
            a0.x = (q.x > 0.0f) ? e0k.x : e0.x;
            a0.y = (q.y > 0.0f) ? e0k.y : e0.y;
            a1.x = (q.x > 0.0f) ? e1k.x : e1.x;
            a1.y = (q.y > 0.0f) ? e1k.y : e1.y;
            // x' = clip(0.95*x + a - gc*hw)
            v2 z0 = fma2(c95, x0, a0);
            z0 = fma2(-gc, hw0s, z0);
            x0 = clamp2(z0);
            v2 z1 = fma2(c95, x1, a1);
            z1 = fma2(-gc, hw1s, z1);
            x1 = clamp2(z1);
        }
        xt0 = x0;
        xt1 = x1;
    }

    v2 bs = b;
    v2 res = fma2(xt0, w0s, fma2(xt1, w1s, bs));
    float2 o;
    o.x = res.x;
    o.y = res.y;
    reinterpret_cast<float2*>(out)[i] = o;
}

extern "C" void kernel_launch(void* const* d_in, const int* in_sizes, int n_in,
                              void* d_out, int out_size, void* d_ws, size_t ws_size,
                              hipStream_t stream) {
    const float* X = (const float*)d_in[0];
    const float* w = (const float*)d_in[1];
    const float* b = (const float*)d_in[2];
    const float* v = (const float*)d_in[3];
    float* out = (float*)d_out;

    int B = in_sizes[0] / 2;   // X is [B, 2]
    int B2 = B / 2;            // 2 samples per thread (packed)
    int block = 256;
    int grid = (B2 + block - 1) / block;
    strategic_kernel<<<grid, block, 0, stream>>>(X, w, b, v, out, B2);
}

// Round 6
// 282.581 us; speedup vs baseline: 3.3933x; 1.0351x over previous
//
#include <hip/hip_runtime.h>

// Problem: MyStrategicModel_35691178229867
// R5 post-mortem: v_pk_fma_f32 is dual-pass on gfx950 (VALUBusy 112->85% with
// flat time) -> per-step cost is at the scalar-issue floor (~16 ops/sample).
// R6: EXACT CCP early-exit. fd_c == fd_{c-1} bitwise => all remaining rounds
// frozen (solve is a deterministic fn of (fd, r)) => skip is bitwise-exact.
// Also handles period-2 fd limit cycles with a parity condition. Wave skips
// when all 64 lanes are frozen (__all). Expected: skip 5-7 of 11 inner solves.

#define XLO -10.0f
#define XHI 10.0f

typedef float v2 __attribute__((ext_vector_type(2)));

__device__ __forceinline__ v2 fma2(v2 a, v2 b, v2 c) {
    return __builtin_elementwise_fma(a, b, c);
}

__device__ __forceinline__ float clampx(float x) {
    return fminf(fmaxf(x, XLO), XHI);   // v_med3_f32
}

__device__ __forceinline__ v2 clamp2(v2 x) {
    v2 r;
    r.x = clampx(x.x);
    r.y = clampx(x.y);
    return r;
}

__device__ __forceinline__ float rsq_nr(float t) {
    float y = __builtin_amdgcn_rsqf(t);
    float c = __builtin_fmaf(-0.5f * (t * y), y, 1.5f);
    return y * c;
}

__global__ __launch_bounds__(256, 8)
void strategic_kernel(const float* __restrict__ X,
                      const float* __restrict__ wp,
                      const float* __restrict__ bp,
                      const float* __restrict__ vp,
                      float* __restrict__ out, int B2) {
    int i = blockIdx.x * blockDim.x + threadIdx.x;
    if (i >= B2) return;

    const float w0 = wp[0], w1 = wp[1], b = bp[0], v0 = vp[0], v1 = vp[1];

    const v2 w0s = w0, w1s = w1, v0s = v0, v1s = v1;
    const v2 bm1s = b - 1.0f;            // score-1 bias (g')
    const v2 bp1s = b + 1.0f;            // score+1 bias (f')
    const v2 hw0s = 0.5f * w0, hw1s = 0.5f * w1;
    const v2 k0s = 0.475f * v0, k1s = 0.475f * v1;   // COST*(1-EPS)*v
    const v2 c95 = 0.95f, one = 1.0f, half = 0.5f, c05 = 0.05f;

    // Samples 2i and 2i+1 packed into v2 lanes.
    float4 r4 = reinterpret_cast<const float4*>(X)[i];
    v2 r0, r1;
    r0.x = r4.x; r0.y = r4.z;   // coord 0 of both samples
    r1.x = r4.y; r1.y = r4.w;   // coord 1 of both samples

    const v2 sx0 = clamp2(r0), sx1 = clamp2(r1);        // inner-solve start
    v2 mvr;
    mvr.x = -(__builtin_fmaf(r1.x, v1, r0.x * v0));
    mvr.y = -(__builtin_fmaf(r1.y, v1, r0.y * v0));
    const v2 p5r0 = c05 * r0, p5r1 = c05 * r1;          // 0.05*r
    v2 xt0 = r0, xt1 = r1;                              // CCP state S_{c-1}

    // fd history for cycle detection (NaN never compares equal)
    v2 fc_p1 = __builtin_nanf(""), fc_p2 = __builtin_nanf("");
    v2 e0, e1, e0k, e1k;

    // 11 CCP rounds. Invariant at break: e-consts == fd(S_10) and xt == S_10.
    int c = 0;
    for (; c < 11; ++c) {
        // fder at xt: fc = 0.5*sp/sqrt(sp^2+1) (NR-refined; 11 calls, cheap)
        v2 sp = fma2(xt0, w0s, fma2(xt1, w1s, bp1s));
        v2 tt = fma2(sp, sp, one);
        v2 rs;
        rs.x = rsq_nr(tt.x);
        rs.y = rsq_nr(tt.y);
        v2 fc = half * sp * rs;
        e0 = fma2(fc, w0s, p5r0);
        e1 = fma2(fc, w1s, p5r1);
        e0k = e0 - k0s;
        e1k = e1 - k1s;

        // Cycle detection BEFORE the solve. per1: F_c == F_{c-1} => the solve
        // would reproduce current xt and fd is frozen forever => S_10 == xt,
        // current e == fd(S_10). per2 (F_c == F_{c-2}): period-2 states from
        // S_{c-2}; break only when S_10 == current xt, i.e. (10-c) odd —
        // otherwise one more round makes the parity line up.
        bool per1 = (fc.x == fc_p1.x) && (fc.y == fc_p1.y);
        bool per2 = (fc.x == fc_p2.x) && (fc.y == fc_p2.y);
        if (__all(per1) || (__all(per2) && ((10 - c) & 1))) break;
        fc_p2 = fc_p1;
        fc_p1 = fc;

        // 100-step projected-gradient solve from clip(r)
        v2 x0 = sx0, x1 = sx1;
        for (int k = 0; k < 100; ++k) {
            v2 tau = fma2(x0, w0s, fma2(x1, w1s, bm1s));
            v2 t2 = fma2(tau, tau, one);
            v2 rq;
            rq.x = __builtin_amdgcn_rsqf(t2.x);
            rq.y = __builtin_amdgcn_rsqf(t2.y);
            v2 gc = tau * rq;
            v2 q = fma2(x0, v0s, fma2(x1, v1s, mvr));
            v2 a0, a1;
            a0.x = (q.x > 0.0f) ? e0k.x : e0.x;
            a0.y = (q.y > 0.0f) ? e0k.y : e0.y;
            a1.x = (q.x > 0.0f) ? e1k.x : e1.x;
            a1.y = (q.y > 0.0f) ? e1k.y : e1.y;
            v2 z0 = fma2(c95, x0, a0);
            z0 = fma2(-gc, hw0s, z0);
            x0 = clamp2(z0);
            v2 z1 = fma2(c95, x1, a1);
            z1 = fma2(-gc, hw1s, z1);
            x1 = clamp2(z1);
        }
        xt0 = x0;
        xt1 = x1;
    }

    // If the loop exhausted naturally, e-consts correspond to fd(S_9);
    // recompute fd at xt = S_10. On early break, e-consts are already fd(S_10).
    if (c == 11) {
        v2 sp = fma2(xt0, w0s, fma2(xt1, w1s, bp1s));
        v2 tt = fma2(sp, sp, one);
        v2 rs;
        rs.x = rsq_nr(tt.x);
        rs.y = rsq_nr(tt.y);
        v2 fc = half * sp * rs;
        e0 = fma2(fc, w0s, p5r0);
        e1 = fma2(fc, w1s, p5r1);
        e0k = e0 - k0s;
        e1k = e1 - k1s;
    }

    // Final (differentiable) solve: 200 steps
    v2 x0 = sx0, x1 = sx1;
    for (int k = 0; k < 200; ++k) {
        v2 tau = fma2(x0, w0s, fma2(x1, w1s, bm1s));
        v2 t2 = fma2(tau, tau, one);
        v2 rq;
        rq.x = __builtin_amdgcn_rsqf(t2.x);
        rq.y = __builtin_amdgcn_rsqf(t2.y);
        v2 gc = tau * rq;
        v2 q = fma2(x0, v0s, fma2(x1, v1s, mvr));
        v2 a0, a1;
        a0.x = (q.x > 0.0f) ? e0k.x : e0.x;
        a0.y = (q.y > 0.0f) ? e0k.y : e0.y;
        a1.x = (q.x > 0.0f) ? e1k.x : e1.x;
        a1.y = (q.y > 0.0f) ? e1k.y : e1.y;
        v2 z0 = fma2(c95, x0, a0);
        z0 = fma2(-gc, hw0s, z0);
        x0 = clamp2(z0);
        v2 z1 = fma2(c95, x1, a1);
        z1 = fma2(-gc, hw1s, z1);
        x1 = clamp2(z1);
    }

    v2 bs = b;
    v2 res = fma2(x0, w0s, fma2(x1, w1s, bs));
    float2 o;
    o.x = res.x;
    o.y = res.y;
    reinterpret_cast<float2*>(out)[i] = o;
}

extern "C" void kernel_launch(void* const* d_in, const int* in_sizes, int n_in,
                              void* d_out, int out_size, void* d_ws, size_t ws_size,
                              hipStream_t stream) {
    const float* X = (const float*)d_in[0];
    const float* w = (const float*)d_in[1];
    const float* b = (const float*)d_in[2];
    const float* v = (const float*)d_in[3];
    float* out = (float*)d_out;

    int B = in_sizes[0] / 2;   // X is [B, 2]
    int B2 = B / 2;            // 2 samples per thread (packed)
    int block = 256;
    int grid = (B2 + block - 1) / block;
    strategic_kernel<<<grid, block, 0, stream>>>(X, w, b, v, out, B2);
}

// Round 7
// 250.486 us; speedup vs baseline: 3.8281x; 1.1281x over previous
//
#include <hip/hip_runtime.h>

// Problem: MyStrategicModel_35691178229867
// R6 post-mortem: at the VALU-issue roofline for the 16-op/step mix
// (38 cyc/sample-step model reproduces 262 us at the ~1.5 GHz sustained
// throttle; v_rsq does NOT overlap VALU issue). Early-exit per-wave ~never
// fires (kept anyway, it's exact and ~free).
// R7: 2-step gc fusion — refresh gc = tau/sqrt(tau^2+1) every 2 steps; the
// kink test (q>0) and box clip stay per-step exact. 30 cyc/step vs 38.
// gc is 1 step stale on odd steps; contraction (0.95/step) kills the
// transient, final iterations are converged => end-state ~unperturbed.

#define XLO -10.0f
#define XHI 10.0f

typedef float v2 __attribute__((ext_vector_type(2)));

__device__ __forceinline__ v2 fma2(v2 a, v2 b, v2 c) {
    return __builtin_elementwise_fma(a, b, c);
}

__device__ __forceinline__ float clampx(float x) {
    return fminf(fmaxf(x, XLO), XHI);   // v_med3_f32
}

__device__ __forceinline__ v2 clamp2(v2 x) {
    v2 r;
    r.x = clampx(x.x);
    r.y = clampx(x.y);
    return r;
}

__device__ __forceinline__ float rsq_nr(float t) {
    float y = __builtin_amdgcn_rsqf(t);
    float c = __builtin_fmaf(-0.5f * (t * y), y, 1.5f);
    return y * c;
}

__global__ __launch_bounds__(256, 8)
void strategic_kernel(const float* __restrict__ X,
                      const float* __restrict__ wp,
                      const float* __restrict__ bp,
                      const float* __restrict__ vp,
                      float* __restrict__ out, int B2) {
    int i = blockIdx.x * blockDim.x + threadIdx.x;
    if (i >= B2) return;

    const float w0 = wp[0], w1 = wp[1], b = bp[0], v0 = vp[0], v1 = vp[1];

    const v2 w0s = w0, w1s = w1, v0s = v0, v1s = v1;
    const v2 bm1s = b - 1.0f;            // score-1 bias (g')
    const v2 bp1s = b + 1.0f;            // score+1 bias (f')
    const v2 hw0s = 0.5f * w0, hw1s = 0.5f * w1;
    const v2 k0s = 0.475f * v0, k1s = 0.475f * v1;   // COST*(1-EPS)*v
    const v2 c95 = 0.95f, one = 1.0f, half = 0.5f, c05 = 0.05f;

    // Samples 2i and 2i+1 packed into v2 lanes.
    float4 r4 = reinterpret_cast<const float4*>(X)[i];
    v2 r0, r1;
    r0.x = r4.x; r0.y = r4.z;   // coord 0 of both samples
    r1.x = r4.y; r1.y = r4.w;   // coord 1 of both samples

    const v2 sx0 = clamp2(r0), sx1 = clamp2(r1);        // inner-solve start
    v2 mvr;
    mvr.x = -(__builtin_fmaf(r1.x, v1, r0.x * v0));
    mvr.y = -(__builtin_fmaf(r1.y, v1, r0.y * v0));
    const v2 p5r0 = c05 * r0, p5r1 = c05 * r1;          // 0.05*r
    v2 xt0 = r0, xt1 = r1;                              // CCP state

    // fd history for exact cycle detection (NaN never compares equal)
    v2 fc_p1 = __builtin_nanf(""), fc_p2 = __builtin_nanf("");
    v2 e0, e1, e0k, e1k;

    int c = 0;
    for (; c < 11; ++c) {
        // fder at xt (NR-refined rsq; 11 calls, cheap)
        v2 sp = fma2(xt0, w0s, fma2(xt1, w1s, bp1s));
        v2 tt = fma2(sp, sp, one);
        v2 rs;
        rs.x = rsq_nr(tt.x);
        rs.y = rsq_nr(tt.y);
        v2 fc = half * sp * rs;
        e0 = fma2(fc, w0s, p5r0);
        e1 = fma2(fc, w1s, p5r1);
        e0k = e0 - k0s;
        e1k = e1 - k1s;

        bool per1 = (fc.x == fc_p1.x) && (fc.y == fc_p1.y);
        bool per2 = (fc.x == fc_p2.x) && (fc.y == fc_p2.y);
        if (__all(per1) || (__all(per2) && ((10 - c) & 1))) break;
        fc_p2 = fc_p1;
        fc_p1 = fc;

        // 100-step solve = 50 fused pairs, gc refreshed per pair
        v2 x0 = sx0, x1 = sx1;
        for (int k = 0; k < 50; ++k) {
            v2 tau = fma2(x0, w0s, fma2(x1, w1s, bm1s));
            v2 t2 = fma2(tau, tau, one);
            v2 rq;
            rq.x = __builtin_amdgcn_rsqf(t2.x);
            rq.y = __builtin_amdgcn_rsqf(t2.y);
            v2 gc = tau * rq;
#pragma unroll
            for (int h = 0; h < 2; ++h) {
                v2 q = fma2(x0, v0s, fma2(x1, v1s, mvr));
                v2 a0, a1;
                a0.x = (q.x > 0.0f) ? e0k.x : e0.x;
                a0.y = (q.y > 0.0f) ? e0k.y : e0.y;
                a1.x = (q.x > 0.0f) ? e1k.x : e1.x;
                a1.y = (q.y > 0.0f) ? e1k.y : e1.y;
                x0 = clamp2(fma2(-gc, hw0s, fma2(c95, x0, a0)));
                x1 = clamp2(fma2(-gc, hw1s, fma2(c95, x1, a1)));
            }
        }
        xt0 = x0;
        xt1 = x1;
    }

    if (c == 11) {   // natural exhaust: e-consts are fd(S_9); refresh at S_10
        v2 sp = fma2(xt0, w0s, fma2(xt1, w1s, bp1s));
        v2 tt = fma2(sp, sp, one);
        v2 rs;
        rs.x = rsq_nr(tt.x);
        rs.y = rsq_nr(tt.y);
        v2 fc = half * sp * rs;
        e0 = fma2(fc, w0s, p5r0);
        e1 = fma2(fc, w1s, p5r1);
        e0k = e0 - k0s;
        e1k = e1 - k1s;
    }

    // Final solve: 200 steps = 100 fused pairs
    v2 x0 = sx0, x1 = sx1;
    for (int k = 0; k < 100; ++k) {
        v2 tau = fma2(x0, w0s, fma2(x1, w1s, bm1s));
        v2 t2 = fma2(tau, tau, one);
        v2 rq;
        rq.x = __builtin_amdgcn_rsqf(t2.x);
        rq.y = __builtin_amdgcn_rsqf(t2.y);
        v2 gc = tau * rq;
#pragma unroll
        for (int h = 0; h < 2; ++h) {
            v2 q = fma2(x0, v0s, fma2(x1, v1s, mvr));
            v2 a0, a1;
            a0.x = (q.x > 0.0f) ? e0k.x : e0.x;
            a0.y = (q.y > 0.0f) ? e0k.y : e0.y;
            a1.x = (q.x > 0.0f) ? e1k.x : e1.x;
            a1.y = (q.y > 0.0f) ? e1k.y : e1.y;
            x0 = clamp2(fma2(-gc, hw0s, fma2(c95, x0, a0)));
            x1 = clamp2(fma2(-gc, hw1s, fma2(c95, x1, a1)));
        }
    }

    v2 bs = b;
    v2 res = fma2(x0, w0s, fma2(x1, w1s, bs));
    float2 o;
    o.x = res.x;
    o.y = res.y;
    reinterpret_cast<float2*>(out)[i] = o;
}

extern "C" void kernel_launch(void* const* d_in, const int* in_sizes, int n_in,
                              void* d_out, int out_size, void* d_ws, size_t ws_size,
                              hipStream_t stream) {
    const float* X = (const float*)d_in[0];
    const float* w = (const float*)d_in[1];
    const float* b = (const float*)d_in[2];
    const float* v = (const float*)d_in[3];
    float* out = (float*)d_out;

    int B = in_sizes[0] / 2;   // X is [B, 2]
    int B2 = B / 2;            // 2 samples per thread (packed)
    int block = 256;
    int grid = (B2 + block - 1) / block;
    strategic_kernel<<<grid, block, 0, stream>>>(X, w, b, v, out, B2);
}

// Round 8
// 221.894 us; speedup vs baseline: 4.3214x; 1.1289x over previous
//
#include <hip/hip_runtime.h>

// Problem: MyStrategicModel_35691178229867
// R7 post-mortem: gc-1-stale was absmax-bitwise-neutral -> gc is a smooth
// drift term; only kink test + clip are sensitivity-critical.
// R8: gc refreshed every 4 steps (3-stale max), with -gc*hw pre-folded into
// both kink-branch constants (4 fma/block). h-step: q(2)+cnd(2)+update(4)=9 pk
// vs 11. Block: 44 pk + 2 rsq = 192 cyc/4 steps = 48 cyc/step (was 60).
// Kink test and box clip stay per-step exact. Early-exit kept (exact, ~free).

#define XLO -10.0f
#define XHI 10.0f

typedef float v2 __attribute__((ext_vector_type(2)));

__device__ __forceinline__ v2 fma2(v2 a, v2 b, v2 c) {
    return __builtin_elementwise_fma(a, b, c);
}

__device__ __forceinline__ float clampx(float x) {
    return fminf(fmaxf(x, XLO), XHI);   // v_med3_f32
}

__device__ __forceinline__ v2 clamp2(v2 x) {
    v2 r;
    r.x = clampx(x.x);
    r.y = clampx(x.y);
    return r;
}

__device__ __forceinline__ float rsq_nr(float t) {
    float y = __builtin_amdgcn_rsqf(t);
    float c = __builtin_fmaf(-0.5f * (t * y), y, 1.5f);
    return y * c;
}

struct P {
    v2 w0s, w1s, v0s, v1s, bm1s, hw0s, hw1s, mvr;
};

// nblocks blocks of 4 PGA steps; gc refreshed per block, folded into the
// kink-branch constants f*/f*k. Kink test + clip exact per step.
__device__ __forceinline__ void solve(int nblocks, v2 sx0, v2 sx1,
                                      v2 e0, v2 e1, v2 e0k, v2 e1k,
                                      const P& p, v2& ox0, v2& ox1) {
    const v2 c95 = 0.95f, one = 1.0f;
    v2 x0 = sx0, x1 = sx1;
    for (int k = 0; k < nblocks; ++k) {
        v2 tau = fma2(x0, p.w0s, fma2(x1, p.w1s, p.bm1s));
        v2 t2 = fma2(tau, tau, one);
        v2 rq;
        rq.x = __builtin_amdgcn_rsqf(t2.x);
        rq.y = __builtin_amdgcn_rsqf(t2.y);
        v2 gc = tau * rq;
        v2 f0  = fma2(-gc, p.hw0s, e0);    // no-kink branch const, gc folded
        v2 f0k = fma2(-gc, p.hw0s, e0k);   // kink branch const
        v2 f1  = fma2(-gc, p.hw1s, e1);
        v2 f1k = fma2(-gc, p.hw1s, e1k);
#pragma unroll
        for (int h = 0; h < 4; ++h) {
            v2 q = fma2(x0, p.v0s, fma2(x1, p.v1s, p.mvr));
            v2 a0, a1;
            a0.x = (q.x > 0.0f) ? f0k.x : f0.x;
            a0.y = (q.y > 0.0f) ? f0k.y : f0.y;
            a1.x = (q.x > 0.0f) ? f1k.x : f1.x;
            a1.y = (q.y > 0.0f) ? f1k.y : f1.y;
            x0 = clamp2(fma2(c95, x0, a0));
            x1 = clamp2(fma2(c95, x1, a1));
        }
    }
    ox0 = x0;
    ox1 = x1;
}

__global__ __launch_bounds__(256, 8)
void strategic_kernel(const float* __restrict__ X,
                      const float* __restrict__ wp,
                      const float* __restrict__ bp,
                      const float* __restrict__ vp,
                      float* __restrict__ out, int B2) {
    int i = blockIdx.x * blockDim.x + threadIdx.x;
    if (i >= B2) return;

    const float w0 = wp[0], w1 = wp[1], b = bp[0], v0 = vp[0], v1 = vp[1];

    P p;
    p.w0s = w0; p.w1s = w1; p.v0s = v0; p.v1s = v1;
    p.bm1s = b - 1.0f;
    p.hw0s = 0.5f * w0; p.hw1s = 0.5f * w1;
    const v2 bp1s = b + 1.0f;
    const v2 k0s = 0.475f * v0, k1s = 0.475f * v1;   // COST*(1-EPS)*v
    const v2 one = 1.0f, half = 0.5f, c05 = 0.05f;

    // Samples 2i and 2i+1 packed into v2 lanes.
    float4 r4 = reinterpret_cast<const float4*>(X)[i];
    v2 r0, r1;
    r0.x = r4.x; r0.y = r4.z;   // coord 0 of both samples
    r1.x = r4.y; r1.y = r4.w;   // coord 1 of both samples

    const v2 sx0 = clamp2(r0), sx1 = clamp2(r1);        // inner-solve start
    p.mvr.x = -(__builtin_fmaf(r1.x, v1, r0.x * v0));
    p.mvr.y = -(__builtin_fmaf(r1.y, v1, r0.y * v0));
    const v2 p5r0 = c05 * r0, p5r1 = c05 * r1;          // 0.05*r
    v2 xt0 = r0, xt1 = r1;                              // CCP state

    // fd history for exact cycle detection (NaN never compares equal)
    v2 fc_p1 = __builtin_nanf(""), fc_p2 = __builtin_nanf("");
    v2 e0, e1, e0k, e1k;

    int c = 0;
    for (; c < 11; ++c) {
        // fder at xt (NR-refined rsq; 11 calls, cheap)
        v2 sp = fma2(xt0, p.w0s, fma2(xt1, p.w1s, bp1s));
        v2 tt = fma2(sp, sp, one);
        v2 rs;
        rs.x = rsq_nr(tt.x);
        rs.y = rsq_nr(tt.y);
        v2 fc = half * sp * rs;
        e0 = fma2(fc, p.w0s, p5r0);
        e1 = fma2(fc, p.w1s, p5r1);
        e0k = e0 - k0s;
        e1k = e1 - k1s;

        bool per1 = (fc.x == fc_p1.x) && (fc.y == fc_p1.y);
        bool per2 = (fc.x == fc_p2.x) && (fc.y == fc_p2.y);
        if (__all(per1) || (__all(per2) && ((10 - c) & 1))) break;
        fc_p2 = fc_p1;
        fc_p1 = fc;

        solve(25, sx0, sx1, e0, e1, e0k, e1k, p, xt0, xt1);  // 100 steps
    }

    if (c == 11) {   // natural exhaust: e-consts are fd(S_9); refresh at S_10
        v2 sp = fma2(xt0, p.w0s, fma2(xt1, p.w1s, bp1s));
        v2 tt = fma2(sp, sp, one);
        v2 rs;
        rs.x = rsq_nr(tt.x);
        rs.y = rsq_nr(tt.y);
        v2 fc = half * sp * rs;
        e0 = fma2(fc, p.w0s, p5r0);
        e1 = fma2(fc, p.w1s, p5r1);
        e0k = e0 - k0s;
        e1k = e1 - k1s;
    }

    // Final (differentiable) solve: 200 steps = 50 blocks
    v2 x0, x1;
    solve(50, sx0, sx1, e0, e1, e0k, e1k, p, x0, x1);

    v2 bs = b;
    v2 res = fma2(x0, p.w0s, fma2(x1, p.w1s, bs));
    float2 o;
    o.x = res.x;
    o.y = res.y;
    reinterpret_cast<float2*>(out)[i] = o;
}

extern "C" void kernel_launch(void* const* d_in, const int* in_sizes, int n_in,
                              void* d_out, int out_size, void* d_ws, size_t ws_size,
                              hipStream_t stream) {
    const float* X = (const float*)d_in[0];
    const float* w = (const float*)d_in[1];
    const float* b = (const float*)d_in[2];
    const float* v = (const float*)d_in[3];
    float* out = (float*)d_out;

    int B = in_sizes[0] / 2;   // X is [B, 2]
    int B2 = B / 2;            // 2 samples per thread (packed)
    int block = 256;
    int grid = (B2 + block - 1) / block;
    strategic_kernel<<<grid, block, 0, stream>>>(X, w, b, v, out, B2);
}